// Round 5
// baseline (478.229 us; speedup 1.0000x reference)
//
#include <hip/hip_runtime.h>
#include <hip/hip_cooperative_groups.h>

namespace cg = cooperative_groups;

typedef unsigned short ushortT;
typedef __attribute__((ext_vector_type(8))) short bf16x8;
typedef __attribute__((ext_vector_type(4))) float f32x4;

constexpr int B_ = 256, P_ = 32, N_ = 60;
constexpr int NE = N_ * (N_ - 1);          // 3540
constexpr int NETOT = B_ * NE;             // 906240
constexpr int ROWS = B_ * N_;              // 15360
constexpr float EPS = 1e-5f;
constexpr int NBLK = 256;                  // 1 block per CU, 1 batch per block

// ---- workspace layout (float offsets) ----
constexpr size_t F_U    = 0;                               // ROWS*64 (b1 folded)
constexpr size_t F_V    = F_U + (size_t)ROWS * 64;         // ROWS*64
constexpr size_t F_XT   = F_V + (size_t)ROWS * 64;         // ROWS*32
constexpr size_t F_BN1S = F_XT + (size_t)ROWS * 32;        // B*64
constexpr size_t F_BN1Q = F_BN1S + (size_t)B_ * 64;        // B*64
constexpr size_t F_SC1  = F_BN1Q + (size_t)B_ * 64;        // 64
constexpr size_t F_SH1  = F_SC1 + 64;                      // 64
constexpr size_t F_W2F  = F_SH1 + 64;                      // 2048
constexpr size_t F_W3F  = F_W2F + 2048;                    // 1024
// zero-init region:
constexpr size_t F_ST2  = F_W3F + 1024;                    // 128
constexpr size_t F_ST3  = F_ST2 + 128;                     // 64
constexpr size_t F_SO1  = F_ST3 + 64;                      // 128
constexpr size_t F_SO2  = F_SO1 + 128;                     // 128
constexpr size_t F_SO3  = F_SO2 + 128;                     // 64
constexpr size_t F_INS  = F_SO3 + 64;                      // 64
constexpr size_t F_END  = F_INS + 64;
constexpr size_t F_MSET     = F_ST2;
constexpr size_t F_MSET_CNT = F_END - F_ST2;
constexpr size_t F_TOTAL    = F_END;

static __device__ __forceinline__ ushortT f2bf(float f) {
    unsigned int u = __float_as_uint(f);
    u += 0x7fffu + ((u >> 16) & 1u);
    return (ushortT)(u >> 16);
}
static __device__ __forceinline__ unsigned int packbf(float lo, float hi) {
    return (unsigned int)f2bf(lo) | ((unsigned int)f2bf(hi) << 16);
}
static __device__ __forceinline__ unsigned int cvtpk(float lo, float hi) {
    unsigned int r;
    asm("v_cvt_pk_bf16_f32 %0, %1, %2" : "=v"(r) : "v"(lo), "v"(hi));
    return r;
}

// ---- K0: input BN raw stats (atomic partials) ----
__global__ __launch_bounds__(256) void k0_part(const float* __restrict__ x,
                                               float* __restrict__ ws) {
    int p = blockIdx.x & 31, seg = blockIdx.x >> 5;
    float s = 0.f, q = 0.f;
    for (int idx = threadIdx.x; idx < 32 * N_; idx += 256) {
        int bb = seg * 32 + idx / N_;
        int n = idx - (idx / N_) * N_;
        float v = x[(size_t)(bb * P_ + p) * N_ + n];
        s += v; q += v * v;
    }
    for (int o = 32; o > 0; o >>= 1) { s += __shfl_down(s, o); q += __shfl_down(q, o); }
    __shared__ float rs[4], rq[4];
    int wid = threadIdx.x >> 6, lane = threadIdx.x & 63;
    if (lane == 0) { rs[wid] = s; rq[wid] = q; }
    __syncthreads();
    if (threadIdx.x == 0) {
        s = rs[0] + rs[1] + rs[2] + rs[3];
        q = rq[0] + rq[1] + rq[2] + rq[3];
        atomicAdd(ws + F_INS + p, s);
        atomicAdd(ws + F_INS + 32 + p, q);
    }
}

// ---- KW: W2 (64x64), W3 (32x64) -> bf16 MFMA fragment layout ----
__global__ __launch_bounds__(256) void kW(const float* __restrict__ w2,
                                          const float* __restrict__ w3,
                                          float* __restrict__ ws) {
    int t = threadIdx.x;
    ushortT* w2f = reinterpret_cast<ushortT*>(ws + F_W2F);
    ushortT* w3f = reinterpret_cast<ushortT*>(ws + F_W3F);
    for (int c = t; c < 512; c += 256) {
        int l = c & 63, s = (c >> 6) & 1, mu = c >> 7;
        int f = mu * 16 + (l & 15);
        int k0 = s * 32 + ((l >> 4) << 3);
        const float* src = w2 + (size_t)f * 64 + k0;
        unsigned int pk[4];
        #pragma unroll
        for (int q = 0; q < 4; ++q) pk[q] = packbf(src[2 * q], src[2 * q + 1]);
        *reinterpret_cast<uint4*>(&w2f[(size_t)c * 8]) = *reinterpret_cast<uint4*>(pk);
    }
    {
        int c = t;
        int l = c & 63, s = (c >> 6) & 1, mu = (c >> 7) & 1;
        int f = mu * 16 + (l & 15);
        int k0 = s * 32 + ((l >> 4) << 3);
        const float* src = w3 + (size_t)f * 64 + k0;
        unsigned int pk[4];
        #pragma unroll
        for (int q = 0; q < 4; ++q) pk[q] = packbf(src[2 * q], src[2 * q + 1]);
        *reinterpret_cast<uint4*>(&w3f[(size_t)c * 8]) = *reinterpret_cast<uint4*>(pk);
    }
}

// ---- K1: inline input-BN finalize; U = xbn W_r^T + b1, V = xbn W_s^T; write xt ----
__global__ __launch_bounds__(256) void k1_uv(const float* __restrict__ x,
                                             const float* __restrict__ w1,
                                             const float* __restrict__ b1,
                                             const float* __restrict__ bnx_g,
                                             const float* __restrict__ bnx_b,
                                             float* __restrict__ ws) {
    int b = blockIdx.x;
    __shared__ float xs[P_ * N_];
    __shared__ float w1t[64 * 65];
    __shared__ float sX[32], tX[32];
    if (threadIdx.x < 32) {
        int p = threadIdx.x;
        float inv = 1.f / (float)(B_ * N_);
        float mean = ws[F_INS + p] * inv;
        float var = ws[F_INS + 32 + p] * inv - mean * mean;
        float sc = bnx_g[p] * rsqrtf(var + EPS);
        sX[p] = sc;
        tX[p] = bnx_b[p] - mean * sc;
    }
    for (int idx = threadIdx.x; idx < 64 * 64; idx += 256) {
        int k = idx >> 6, c = idx & 63;
        w1t[c * 65 + k] = w1[idx];
    }
    __syncthreads();
    for (int idx = threadIdx.x; idx < P_ * N_; idx += 256) {
        int p = idx / N_, n = idx - (idx / N_) * N_;
        xs[idx] = sX[p] * x[(size_t)(b * P_ + p) * N_ + n] + tX[p];
    }
    __syncthreads();
    for (int idx = threadIdx.x; idx < N_ * P_; idx += 256) {
        int n = idx / P_, p = idx - (idx / P_) * P_;
        ws[F_XT + (size_t)(b * N_ + n) * P_ + p] = xs[p * N_ + n];
    }
    const int k = threadIdx.x & 63;
    float wu[32], wv[32];
    #pragma unroll
    for (int p = 0; p < 32; ++p) {
        wu[p] = w1t[p * 65 + k];
        wv[p] = w1t[(32 + p) * 65 + k];
    }
    const float b1k = b1[k];
    for (int idx = threadIdx.x; idx < N_ * 64; idx += 256) {
        int n = idx >> 6;
        float u = b1k, v = 0.f;
        #pragma unroll
        for (int p = 0; p < 32; ++p) {
            float xv = xs[p * N_ + n];
            u += xv * wu[p];
            v += xv * wv[p];
        }
        ws[F_U + (size_t)(b * N_ + n) * 64 + k] = u;
        ws[F_V + (size_t)(b * N_ + n) * 64 + k] = v;
    }
}

// ---- K2: per-batch closed-form BN1 partials ----
__global__ __launch_bounds__(64) void k2_bn1(float* __restrict__ ws) {
    int b = blockIdx.x, k = threadIdx.x;
    const float* Up = ws + F_U + (size_t)b * N_ * 64;
    const float* Vp = ws + F_V + (size_t)b * N_ * 64;
    float su = 0, sv = 0, suu = 0, svv = 0, suv = 0;
    for (int n = 0; n < N_; ++n) {
        float u = Up[n * 64 + k], v = Vp[n * 64 + k];
        su += u; sv += v; suu += u * u; svv += v * v; suv += u * v;
    }
    ws[F_BN1S + b * 64 + k] = 59.f * (su + sv);
    ws[F_BN1Q + b * 64 + k] = 59.f * (suu + svv) + 2.f * (su * sv - suv);
}

// ---- K3: finalize BN1 ----
__global__ __launch_bounds__(256) void k3_fin1(const float* __restrict__ g,
                                               const float* __restrict__ be,
                                               float* __restrict__ ws) {
    int k = threadIdx.x & 63, part = threadIdx.x >> 6;
    float S = 0, Q = 0;
    for (int b = part; b < B_; b += 4) {
        S += ws[F_BN1S + b * 64 + k];
        Q += ws[F_BN1Q + b * 64 + k];
    }
    __shared__ float rs[4][64], rq[4][64];
    rs[part][k] = S; rq[part][k] = Q;
    __syncthreads();
    if (threadIdx.x < 64) {
        S = rs[0][k] + rs[1][k] + rs[2][k] + rs[3][k];
        Q = rq[0][k] + rq[1][k] + rq[2][k] + rq[3][k];
        float inv = 1.f / (float)NETOT;
        float mean = S * inv;
        float var = Q * inv - mean * mean;
        float sc = g[k] * rsqrtf(var + EPS);
        ws[F_SC1 + k] = sc;
        ws[F_SH1 + k] = be[k] - mean * sc;
    }
}

// ---- shared-mem byte offsets for kfused ----
constexpr int SM_UV  = 0;        // [120][68] f : V'(0..59), U'(60..119)  (32640)
constexpr int SM_E1  = 32640;    // e1 frags (8192)
constexpr int SM_E2  = 40832;    // e2 frags (8192)
constexpr int SM_EB  = 49024;    // ebar [60][32] f (7680)
constexpr int SM_BN  = 56704;    // 320 f (1280)
constexpr int SM_RED = 57984;    // 512 f (2048)
constexpr int SM_TOT = 60032;
// overlays (edge-phase regions dead in object phase):
constexpr int SM_WT  = 0;        // [64][68] f (17408)
constexpr int SM_XT2 = 17408;    // [60][32] f (7680); later ho3
constexpr int SM_RO  = 25088;    // 128 f (512)
constexpr int SM_HO  = 32640;    // [60][64] f (15360), over e1+e2

__device__ __forceinline__ void build_e1(int t, int i,
                                         const float* __restrict__ sUV,
                                         ushortT* __restrict__ e1f) {
    int l = t & 63, s = (t >> 6) & 1, m = t >> 7;
    int e_loc = (m << 4) + (l & 15);
    int k0 = (s << 5) + ((l >> 4) << 3);
    uint4 outv = {0u, 0u, 0u, 0u};
    if (e_loc < 59) {
        int j = e_loc + (e_loc >= i ? 1 : 0);
        const float* up = sUV + (60 + i) * 68 + k0;
        const float* vp = sUV + j * 68 + k0;
        float4 ua = *reinterpret_cast<const float4*>(up);
        float4 ub = *reinterpret_cast<const float4*>(up + 4);
        float4 va = *reinterpret_cast<const float4*>(vp);
        float4 vb = *reinterpret_cast<const float4*>(vp + 4);
        outv.x = cvtpk(fmaxf(0.f, ua.x + va.x), fmaxf(0.f, ua.y + va.y));
        outv.y = cvtpk(fmaxf(0.f, ua.z + va.z), fmaxf(0.f, ua.w + va.w));
        outv.z = cvtpk(fmaxf(0.f, ub.x + vb.x), fmaxf(0.f, ub.y + vb.y));
        outv.w = cvtpk(fmaxf(0.f, ub.z + vb.z), fmaxf(0.f, ub.w + vb.w));
    }
    *reinterpret_cast<uint4*>(e1f + (size_t)t * 8) = outv;
}

__device__ __forceinline__ void fo_accum(const float* __restrict__ sIn, int pitch,
                                         const float* __restrict__ sWt,
                                         int kEnd, int r0, int o0,
                                         float fa[4][4]) {
    for (int k4 = 0; k4 < kEnd; k4 += 4) {
        float4 w0 = *reinterpret_cast<const float4*>(sWt + (k4 + 0) * 68 + o0);
        float4 w1 = *reinterpret_cast<const float4*>(sWt + (k4 + 1) * 68 + o0);
        float4 w2 = *reinterpret_cast<const float4*>(sWt + (k4 + 2) * 68 + o0);
        float4 w3 = *reinterpret_cast<const float4*>(sWt + (k4 + 3) * 68 + o0);
        #pragma unroll
        for (int j = 0; j < 4; ++j) {
            float4 iv = *reinterpret_cast<const float4*>(sIn + (r0 + j) * pitch + k4);
            fa[j][0] += iv.x * w0.x + iv.y * w1.x + iv.z * w2.x + iv.w * w3.x;
            fa[j][1] += iv.x * w0.y + iv.y * w1.y + iv.z * w2.y + iv.w * w3.y;
            fa[j][2] += iv.x * w0.z + iv.y * w1.z + iv.z * w2.z + iv.w * w3.z;
            fa[j][3] += iv.x * w0.w + iv.y * w1.w + iv.z * w2.w + iv.w * w3.w;
        }
    }
}

__global__ __launch_bounds__(512, 2) void kfused(
    float* __restrict__ ws,
    const float* __restrict__ fr2_g, const float* __restrict__ fr2_be,
    const float* __restrict__ fr3_g, const float* __restrict__ fr3_be,
    const float* __restrict__ fo1_w, const float* __restrict__ fo1_g, const float* __restrict__ fo1_be,
    const float* __restrict__ fo2_w, const float* __restrict__ fo2_g, const float* __restrict__ fo2_be,
    const float* __restrict__ fo3_w, const float* __restrict__ fo3_g, const float* __restrict__ fo3_be,
    const float* __restrict__ fc_w, const float* __restrict__ fc_b,
    float* __restrict__ out)
{
    __shared__ __align__(16) char smem[SM_TOT];
    float*   sUV   = reinterpret_cast<float*>(smem + SM_UV);
    ushortT* e1f   = reinterpret_cast<ushortT*>(smem + SM_E1);
    ushortT* e2f   = reinterpret_cast<ushortT*>(smem + SM_E2);
    float*   sEbar = reinterpret_cast<float*>(smem + SM_EB);
    float*   sBN   = reinterpret_cast<float*>(smem + SM_BN);
    float*   red   = reinterpret_cast<float*>(smem + SM_RED);
    float*   sWt   = reinterpret_cast<float*>(smem + SM_WT);
    float*   sxt   = reinterpret_cast<float*>(smem + SM_XT2);
    float*   redO  = reinterpret_cast<float*>(smem + SM_RO);
    float*   hoP   = reinterpret_cast<float*>(smem + SM_HO);
    float*   ho3   = reinterpret_cast<float*>(smem + SM_XT2);

    cg::grid_group grid = cg::this_grid();
    const int b = blockIdx.x;
    const int t = threadIdx.x;
    const int w = t >> 6, lane = t & 63;
    const int gq = lane >> 4, ln = lane & 15;
    const int nu = w & 3, mh = w >> 2;     // phase-1 task
    const int et = w & 3, fh = w >> 2;     // phase-3/5 task (et=edge tile, fh=feature half / nv)
    const f32x4 zero = {0.f, 0.f, 0.f, 0.f};

    // sc1/sh1 -> sBN[0..127]
    if (t < 128) sBN[t] = ws[F_SC1 + t];
    __syncthreads();
    // V' = sc1*V (rows 0..59), U' = sc1*U + sh1 (rows 60..119)
    {
        const float* Vg = ws + F_V + (size_t)b * N_ * 64;
        const float* Ug = ws + F_U + (size_t)b * N_ * 64;
        for (int idx = t; idx < 120 * 16; idx += 512) {
            int r = idx >> 4, c4 = (idx & 15) << 2;
            float4 sc = *reinterpret_cast<const float4*>(sBN + c4);
            float4 sh = *reinterpret_cast<const float4*>(sBN + 64 + c4);
            float4 v;
            if (r < 60) {
                v = *reinterpret_cast<const float4*>(Vg + (size_t)r * 64 + c4);
                v.x *= sc.x; v.y *= sc.y; v.z *= sc.z; v.w *= sc.w;
            } else {
                v = *reinterpret_cast<const float4*>(Ug + (size_t)(r - 60) * 64 + c4);
                v.x = sc.x * v.x + sh.x; v.y = sc.y * v.y + sh.y;
                v.z = sc.z * v.z + sh.z; v.w = sc.w * v.w + sh.w;
            }
            *reinterpret_cast<float4*>(sUV + r * 68 + c4) = v;
        }
    }
    // wave-private weight fragments (wave-uniform addresses -> registers)
    const bf16x8* __restrict__ w2fr = reinterpret_cast<const bf16x8*>(ws + F_W2F);
    const bf16x8* __restrict__ w3fr = reinterpret_cast<const bf16x8*>(ws + F_W3F);
    const bf16x8 bw0 = w2fr[(nu * 2 + 0) * 64 + lane];          // phase-1 B (feature tile nu)
    const bf16x8 bw1 = w2fr[(nu * 2 + 1) * 64 + lane];
    const bf16x8 a00 = w2fr[((2 * fh + 0) * 2 + 0) * 64 + lane]; // phase-3/5 A (mu = 2fh+q)
    const bf16x8 a01 = w2fr[((2 * fh + 0) * 2 + 1) * 64 + lane];
    const bf16x8 a10 = w2fr[((2 * fh + 1) * 2 + 0) * 64 + lane];
    const bf16x8 a11 = w2fr[((2 * fh + 1) * 2 + 1) * 64 + lane];
    const bf16x8 c0w = w3fr[(fh * 2 + 0) * 64 + lane];           // h3 B (nv = fh)
    const bf16x8 c1w = w3fr[(fh * 2 + 1) * 64 + lane];
    const bf16x8* e1c = reinterpret_cast<const bf16x8*>(e1f);
    const bf16x8* e2c = reinterpret_cast<const bf16x8*>(e2f);
    __syncthreads();

    // ================= phase 1: raw h2 stats =================
    {
        float st0 = 0.f, st1 = 0.f;
        for (int i = 0; i < N_; ++i) {
            build_e1(t, i, sUV, e1f);
            __syncthreads();
            f32x4 acc0 = zero, acc1 = zero;
            acc0 = __builtin_amdgcn_mfma_f32_16x16x32_bf16(e1c[(4 * mh + 0) * 64 + lane], bw0, acc0, 0, 0, 0);
            acc0 = __builtin_amdgcn_mfma_f32_16x16x32_bf16(e1c[(4 * mh + 1) * 64 + lane], bw1, acc0, 0, 0, 0);
            acc1 = __builtin_amdgcn_mfma_f32_16x16x32_bf16(e1c[(4 * mh + 2) * 64 + lane], bw0, acc1, 0, 0, 0);
            acc1 = __builtin_amdgcn_mfma_f32_16x16x32_bf16(e1c[(4 * mh + 3) * 64 + lane], bw1, acc1, 0, 0, 0);
            #pragma unroll
            for (int r = 0; r < 4; ++r) {
                st0 += acc0[r] + acc1[r];
                st1 += acc0[r] * acc0[r] + acc1[r] * acc1[r];
            }
            __syncthreads();
        }
        st0 += __shfl_xor(st0, 16); st1 += __shfl_xor(st1, 16);
        st0 += __shfl_xor(st0, 32); st1 += __shfl_xor(st1, 32);
        if (lane < 16) { red[w * 32 + ln] = st0; red[256 + w * 32 + ln] = st1; }
        __syncthreads();
        if (t < 64) {
            int n_ = t >> 4, l_ = t & 15;
            atomicAdd(ws + F_ST2 + t, red[n_ * 32 + l_] + red[(n_ + 4) * 32 + l_]);
        } else if (t < 128) {
            int f = t - 64, n_ = f >> 4, l_ = f & 15;
            atomicAdd(ws + F_ST2 + t, red[256 + n_ * 32 + l_] + red[256 + (n_ + 4) * 32 + l_]);
        }
    }
    __threadfence();
    grid.sync();
    if (t < 64) {
        float S = ws[F_ST2 + t], Q = ws[F_ST2 + 64 + t];
        float m = S * (1.f / (float)NETOT);
        float var = Q * (1.f / (float)NETOT) - m * m;
        float sc = fr2_g[t] * rsqrtf(var + EPS);
        sBN[128 + t] = sc;
        sBN[192 + t] = fr2_be[t] - m * sc;
    }
    __syncthreads();

    // ================= phase 3: e2 = relu(bn2(h2)), raw h3 stats =================
    {
        float st0 = 0.f, st1 = 0.f;
        const bool edge_ok = (et * 16 + ln) < 59;
        for (int i = 0; i < N_; ++i) {
            build_e1(t, i, sUV, e1f);
            __syncthreads();
            bf16x8 be0 = e1c[(et * 2 + 0) * 64 + lane];
            bf16x8 be1 = e1c[(et * 2 + 1) * 64 + lane];
            f32x4 p0 = zero, p1 = zero;
            p0 = __builtin_amdgcn_mfma_f32_16x16x32_bf16(a00, be0, p0, 0, 0, 0);
            p0 = __builtin_amdgcn_mfma_f32_16x16x32_bf16(a01, be1, p0, 0, 0, 0);
            p1 = __builtin_amdgcn_mfma_f32_16x16x32_bf16(a10, be0, p1, 0, 0, 0);
            p1 = __builtin_amdgcn_mfma_f32_16x16x32_bf16(a11, be1, p1, 0, 0, 0);
            #pragma unroll
            for (int q = 0; q < 2; ++q) {
                f32x4 pp = q ? p1 : p0;
                int mu = 2 * fh + q;
                int fb = mu * 16 + gq * 4;
                float4 s2v = *reinterpret_cast<const float4*>(sBN + 128 + fb);
                float4 h2s = *reinterpret_cast<const float4*>(sBN + 192 + fb);
                float e0 = fmaxf(0.f, s2v.x * pp[0] + h2s.x);
                float e1v = fmaxf(0.f, s2v.y * pp[1] + h2s.y);
                float e2v = fmaxf(0.f, s2v.z * pp[2] + h2s.z);
                float e3v = fmaxf(0.f, s2v.w * pp[3] + h2s.w);
                unsigned int pk0 = cvtpk(e0, e1v), pk1 = cvtpk(e2v, e3v);
                if (!edge_ok) { pk0 = 0u; pk1 = 0u; }
                int lp = ln + (q << 5) + ((gq >> 1) << 4);
                int base = ((et * 2 + fh) * 64 + lp) * 8 + ((gq & 1) << 2);
                uint2 pr; pr.x = pk0; pr.y = pk1;
                *reinterpret_cast<uint2*>(&e2f[base]) = pr;
            }
            __syncthreads();
            f32x4 q3 = zero;
            q3 = __builtin_amdgcn_mfma_f32_16x16x32_bf16(e2c[(et * 2 + 0) * 64 + lane], c0w, q3, 0, 0, 0);
            q3 = __builtin_amdgcn_mfma_f32_16x16x32_bf16(e2c[(et * 2 + 1) * 64 + lane], c1w, q3, 0, 0, 0);
            #pragma unroll
            for (int r = 0; r < 4; ++r) { st0 += q3[r]; st1 += q3[r] * q3[r]; }
        }
        st0 += __shfl_xor(st0, 16); st1 += __shfl_xor(st1, 16);
        st0 += __shfl_xor(st0, 32); st1 += __shfl_xor(st1, 32);
        __syncthreads();
        if (lane < 16) { red[w * 32 + ln] = st0; red[256 + w * 32 + ln] = st1; }
        __syncthreads();
        if (t < 32) {
            int n_ = t >> 4, l_ = t & 15, base = 4 * n_;
            float S = red[(base + 0) * 32 + l_] + red[(base + 1) * 32 + l_]
                    + red[(base + 2) * 32 + l_] + red[(base + 3) * 32 + l_];
            atomicAdd(ws + F_ST3 + t, S);
        } else if (t < 64) {
            int f = t - 32, n_ = f >> 4, l_ = f & 15, base = 4 * n_;
            float Q = red[256 + (base + 0) * 32 + l_] + red[256 + (base + 1) * 32 + l_]
                    + red[256 + (base + 2) * 32 + l_] + red[256 + (base + 3) * 32 + l_];
            atomicAdd(ws + F_ST3 + t, Q);
        }
    }
    __threadfence();
    grid.sync();
    if (t < 32) {
        float S = ws[F_ST3 + t], Q = ws[F_ST3 + 32 + t];
        float m = S * (1.f / (float)NETOT);
        float var = Q * (1.f / (float)NETOT) - m * m;
        float sc = fr3_g[t] * rsqrtf(var + EPS);
        sBN[256 + t] = sc;
        sBN[288 + t] = fr3_be[t] - m * sc;
    }
    __syncthreads();

    // ================= phase 5: recompute + bn3relu + EBAR (LDS) =================
    {
        const bool edge_ok = (et * 16 + ln) < 59;
        const float s3 = sBN[256 + fh * 16 + ln];
        const float t3 = sBN[288 + fh * 16 + ln];
        for (int i = 0; i < N_; ++i) {
            build_e1(t, i, sUV, e1f);
            __syncthreads();
            bf16x8 be0 = e1c[(et * 2 + 0) * 64 + lane];
            bf16x8 be1 = e1c[(et * 2 + 1) * 64 + lane];
            f32x4 p0 = zero, p1 = zero;
            p0 = __builtin_amdgcn_mfma_f32_16x16x32_bf16(a00, be0, p0, 0, 0, 0);
            p0 = __builtin_amdgcn_mfma_f32_16x16x32_bf16(a01, be1, p0, 0, 0, 0);
            p1 = __builtin_amdgcn_mfma_f32_16x16x32_bf16(a10, be0, p1, 0, 0, 0);
            p1 = __builtin_amdgcn_mfma_f32_16x16x32_bf16(a11, be1, p1, 0, 0, 0);
            #pragma unroll
            for (int q = 0; q < 2; ++q) {
                f32x4 pp = q ? p1 : p0;
                int mu = 2 * fh + q;
                int fb = mu * 16 + gq * 4;
                float4 s2v = *reinterpret_cast<const float4*>(sBN + 128 + fb);
                float4 h2s = *reinterpret_cast<const float4*>(sBN + 192 + fb);
                float e0 = fmaxf(0.f, s2v.x * pp[0] + h2s.x);
                float e1v = fmaxf(0.f, s2v.y * pp[1] + h2s.y);
                float e2v = fmaxf(0.f, s2v.z * pp[2] + h2s.z);
                float e3v = fmaxf(0.f, s2v.w * pp[3] + h2s.w);
                unsigned int pk0 = cvtpk(e0, e1v), pk1 = cvtpk(e2v, e3v);
                if (!edge_ok) { pk0 = 0u; pk1 = 0u; }
                int lp = ln + (q << 5) + ((gq >> 1) << 4);
                int base = ((et * 2 + fh) * 64 + lp) * 8 + ((gq & 1) << 2);
                uint2 pr; pr.x = pk0; pr.y = pk1;
                *reinterpret_cast<uint2*>(&e2f[base]) = pr;
            }
            __syncthreads();
            f32x4 q3 = zero;
            q3 = __builtin_amdgcn_mfma_f32_16x16x32_bf16(e2c[(et * 2 + 0) * 64 + lane], c0w, q3, 0, 0, 0);
            q3 = __builtin_amdgcn_mfma_f32_16x16x32_bf16(e2c[(et * 2 + 1) * 64 + lane], c1w, q3, 0, 0, 0);
            float es = 0.f;
            #pragma unroll
            for (int r = 0; r < 4; ++r) {
                if (et * 16 + gq * 4 + r < 59)
                    es += fmaxf(0.f, s3 * q3[r] + t3);
            }
            es += __shfl_xor(es, 16);
            es += __shfl_xor(es, 32);
            if (lane < 16) red[w * 32 + ln] = es;
            __syncthreads();
            if (t < 32) {
                int n_ = t >> 4, l_ = t & 15, base = 4 * n_;
                sEbar[i * 32 + t] = red[(base + 0) * 32 + l_] + red[(base + 1) * 32 + l_]
                                  + red[(base + 2) * 32 + l_] + red[(base + 3) * 32 + l_];
            }
        }
    }
    __syncthreads();

    // ================= object path (60 rows of this batch, all LDS) =================
    float fa[4][4];
    const bool act = (t < 240);
    const int r0 = (t >> 4) << 2, o0 = (t & 15) << 2;   // for 240-thread layers
    // ---- fo1 ----
    for (int idx = t; idx < 4096; idx += 512) {
        int o = idx >> 6, k = idx & 63;
        sWt[k * 68 + o] = fo1_w[idx];
    }
    {
        const float* xg = ws + F_XT + (size_t)b * N_ * 32;
        for (int idx = t; idx < 480; idx += 512)
            *reinterpret_cast<float4*>(sxt + idx * 4) = *reinterpret_cast<const float4*>(xg + idx * 4);
    }
    if (t < 128) redO[t] = 0.f;
    __syncthreads();
    if (act) {
        #pragma unroll
        for (int j = 0; j < 4; ++j)
            #pragma unroll
            for (int c = 0; c < 4; ++c) fa[j][c] = 0.f;
        fo_accum(sxt, 32, sWt, 32, r0, o0, fa);
        fo_accum(sEbar, 32, sWt + 32 * 68, 32, r0, o0, fa);
        float ls[4] = {0, 0, 0, 0}, lq[4] = {0, 0, 0, 0};
        #pragma unroll
        for (int j = 0; j < 4; ++j)
            #pragma unroll
            for (int c = 0; c < 4; ++c) { float h = fa[j][c]; ls[c] += h; lq[c] += h * h; }
        #pragma unroll
        for (int c = 0; c < 4; ++c) {
            atomicAdd(&redO[o0 + c], ls[c]);
            atomicAdd(&redO[64 + o0 + c], lq[c]);
        }
    }
    __syncthreads();
    if (t < 128) atomicAdd(ws + F_SO1 + t, redO[t]);
    __threadfence();
    grid.sync();
    if (t < 64) {
        float S = ws[F_SO1 + t], Q = ws[F_SO1 + 64 + t];
        float m = S * (1.f / (float)ROWS);
        float var = Q * (1.f / (float)ROWS) - m * m;
        float sc = fo1_g[t] * rsqrtf(var + EPS);
        sBN[t] = sc; sBN[64 + t] = fo1_be[t] - m * sc;
    }
    __syncthreads();
    if (act) {
        #pragma unroll
        for (int j = 0; j < 4; ++j)
            #pragma unroll
            for (int c = 0; c < 4; ++c) {
                int o = o0 + c;
                hoP[(r0 + j) * 64 + o] = fmaxf(0.f, sBN[o] * fa[j][c] + sBN[64 + o]);
            }
    }
    // ---- fo2 ----
    for (int idx = t; idx < 4096; idx += 512) {
        int o = idx >> 6, k = idx & 63;
        sWt[k * 68 + o] = fo2_w[idx];
    }
    if (t < 128) redO[t] = 0.f;
    __syncthreads();
    if (act) {
        #pragma unroll
        for (int j = 0; j < 4; ++j)
            #pragma unroll
            for (int c = 0; c < 4; ++c) fa[j][c] = 0.f;
        fo_accum(hoP, 64, sWt, 64, r0, o0, fa);
        float ls[4] = {0, 0, 0, 0}, lq[4] = {0, 0, 0, 0};
        #pragma unroll
        for (int j = 0; j < 4; ++j)
            #pragma unroll
            for (int c = 0; c < 4; ++c) { float h = fa[j][c]; ls[c] += h; lq[c] += h * h; }
        #pragma unroll
        for (int c = 0; c < 4; ++c) {
            atomicAdd(&redO[o0 + c], ls[c]);
            atomicAdd(&redO[64 + o0 + c], lq[c]);
        }
    }
    __syncthreads();
    if (t < 128) atomicAdd(ws + F_SO2 + t, redO[t]);
    __threadfence();
    grid.sync();
    if (t < 64) {
        float S = ws[F_SO2 + t], Q = ws[F_SO2 + 64 + t];
        float m = S * (1.f / (float)ROWS);
        float var = Q * (1.f / (float)ROWS) - m * m;
        float sc = fo2_g[t] * rsqrtf(var + EPS);
        sBN[t] = sc; sBN[64 + t] = fo2_be[t] - m * sc;
    }
    __syncthreads();
    if (act) {
        #pragma unroll
        for (int j = 0; j < 4; ++j)
            #pragma unroll
            for (int c = 0; c < 4; ++c) {
                int o = o0 + c;
                hoP[(r0 + j) * 64 + o] = fmaxf(0.f, sBN[o] * fa[j][c] + sBN[64 + o]);
            }
    }
    // ---- fo3 ----
    for (int idx = t; idx < 2048; idx += 512) {
        int o = idx >> 6, k = idx & 63;
        sWt[k * 68 + o] = fo3_w[idx];
    }
    if (t < 64) redO[t] = 0.f;
    __syncthreads();
    const bool act3 = (t < 120);
    const int r3 = (t >> 3) << 2, o3 = (t & 7) << 2;
    if (act3) {
        #pragma unroll
        for (int j = 0; j < 4; ++j)
            #pragma unroll
            for (int c = 0; c < 4; ++c) fa[j][c] = 0.f;
        fo_accum(hoP, 64, sWt, 64, r3, o3, fa);
        float ls[4] = {0, 0, 0, 0}, lq[4] = {0, 0, 0, 0};
        #pragma unroll
        for (int j = 0; j < 4; ++j)
            #pragma unroll
            for (int c = 0; c < 4; ++c) { float h = fa[j][c]; ls[c] += h; lq[c] += h * h; }
        #pragma unroll
        for (int c = 0; c < 4; ++c) {
            atomicAdd(&redO[o3 + c], ls[c]);
            atomicAdd(&redO[32 + o3 + c], lq[c]);
        }
    }
    __syncthreads();
    if (t < 64) atomicAdd(ws + F_SO3 + t, redO[t]);
    __threadfence();
    grid.sync();
    if (t < 32) {
        float S = ws[F_SO3 + t], Q = ws[F_SO3 + 32 + t];
        float m = S * (1.f / (float)ROWS);
        float var = Q * (1.f / (float)ROWS) - m * m;
        float sc = fo3_g[t] * rsqrtf(var + EPS);
        sBN[t] = sc; sBN[32 + t] = fo3_be[t] - m * sc;
    }
    __syncthreads();
    if (act3) {
        #pragma unroll
        for (int j = 0; j < 4; ++j)
            #pragma unroll
            for (int c = 0; c < 4; ++c) {
                int o = o3 + c;
                ho3[(r3 + j) * 32 + o] = fmaxf(0.f, sBN[o] * fa[j][c] + sBN[32 + o]);
            }
    }
    __syncthreads();
    // ---- pool over n + fc (block-local) ----
    if (t < 32) {
        float a = 0.f;
        for (int r = 0; r < N_; ++r) a += ho3[r * 32 + t];
        sBN[128 + t] = a;
    }
    __syncthreads();
    if (t < 64) {
        int o = t >> 5, f = t & 31;
        float p = sBN[128 + f] * fc_w[o * 32 + f];
        p += __shfl_xor(p, 1); p += __shfl_xor(p, 2); p += __shfl_xor(p, 4);
        p += __shfl_xor(p, 8); p += __shfl_xor(p, 16);
        if ((t & 31) == 0) out[b * 2 + o] = p + fc_b[o];
    }
}

extern "C" void kernel_launch(void* const* d_in, const int* in_sizes, int n_in,
                              void* d_out, int out_size, void* d_ws, size_t ws_size,
                              hipStream_t stream) {
    const float* x      = (const float*)d_in[0];
    const float* bnx_g  = (const float*)d_in[1];
    const float* bnx_b  = (const float*)d_in[2];
    const float* fr1_w  = (const float*)d_in[3];
    const float* fr1_b  = (const float*)d_in[4];
    const float* fr1_g  = (const float*)d_in[5];
    const float* fr1_be = (const float*)d_in[6];
    const float* fr2_w  = (const float*)d_in[7];
    const float* fr2_g  = (const float*)d_in[9];
    const float* fr2_be = (const float*)d_in[10];
    const float* fr3_w  = (const float*)d_in[11];
    const float* fr3_g  = (const float*)d_in[13];
    const float* fr3_be = (const float*)d_in[14];
    const float* fo1_w  = (const float*)d_in[15];
    const float* fo1_g  = (const float*)d_in[17];
    const float* fo1_be = (const float*)d_in[18];
    const float* fo2_w  = (const float*)d_in[19];
    const float* fo2_g  = (const float*)d_in[21];
    const float* fo2_be = (const float*)d_in[22];
    const float* fo3_w  = (const float*)d_in[23];
    const float* fo3_g  = (const float*)d_in[25];
    const float* fo3_be = (const float*)d_in[26];
    const float* fc_w   = (const float*)d_in[27];
    const float* fc_b   = (const float*)d_in[28];

    float* ws = (float*)d_ws;
    float* out = (float*)d_out;
    if (ws_size < F_TOTAL * sizeof(float)) return;

    hipMemsetAsync(ws + F_MSET, 0, F_MSET_CNT * sizeof(float), stream);
    kW<<<1, 256, 0, stream>>>(fr2_w, fr3_w, ws);
    k0_part<<<256, 256, 0, stream>>>(x, ws);
    k1_uv<<<B_, 256, 0, stream>>>(x, fr1_w, fr1_b, bnx_g, bnx_b, ws);
    k2_bn1<<<B_, 64, 0, stream>>>(ws);
    k3_fin1<<<1, 256, 0, stream>>>(fr1_g, fr1_be, ws);

    void* kargs[17];
    kargs[0]  = (void*)&ws;
    kargs[1]  = (void*)&fr2_g;  kargs[2]  = (void*)&fr2_be;
    kargs[3]  = (void*)&fr3_g;  kargs[4]  = (void*)&fr3_be;
    kargs[5]  = (void*)&fo1_w;  kargs[6]  = (void*)&fo1_g;  kargs[7]  = (void*)&fo1_be;
    kargs[8]  = (void*)&fo2_w;  kargs[9]  = (void*)&fo2_g;  kargs[10] = (void*)&fo2_be;
    kargs[11] = (void*)&fo3_w;  kargs[12] = (void*)&fo3_g;  kargs[13] = (void*)&fo3_be;
    kargs[14] = (void*)&fc_w;   kargs[15] = (void*)&fc_b;
    kargs[16] = (void*)&out;
    hipLaunchCooperativeKernel((const void*)kfused, dim3(NBLK), dim3(512), kargs, 0, stream);
}